// Round 11
// baseline (225.246 us; speedup 1.0000x reference)
//
#include <hip/hip_runtime.h>
#include <hip/hip_bf16.h>
#include <stdint.h>

typedef __attribute__((ext_vector_type(4))) float f32x4;
typedef __attribute__((ext_vector_type(8))) short s16x8;
typedef __attribute__((ext_vector_type(4))) unsigned int u32x4;
typedef unsigned short u16;
typedef unsigned int u32;

#define B_ 4
#define C_ 256
#define O_ 256
#define H_ 96
#define W_ 96
#define HW_ (H_*W_)      /* 9216 */
#define M_ (B_*HW_)      /* 36864 */

static __device__ __forceinline__ float asf(u32 u){
    union { u32 u; float f; } x; x.u = u; return x.f;
}
static __device__ __forceinline__ u16 f2bf(float f){
    union { float f; u32 u; } x; x.f = f;
    u32 u = x.u;
    u32 r = (u + 0x7fffu + ((u >> 16) & 1u)) >> 16;
    return (u16)r;
}
// bilinear-combine a bf16 pair (packed in u32) from 4 source pairs, repack
static __device__ __forceinline__ u32 blerp_pack(u32 q00, u32 q01, u32 q10, u32 q11,
                                                 float w00, float w01, float w10, float w11)
{
    float f0 = asf(q00 << 16) * w00 + asf(q01 << 16) * w01
             + asf(q10 << 16) * w10 + asf(q11 << 16) * w11;
    float f1 = asf(q00) * w00 + asf(q01) * w01 + asf(q10) * w10 + asf(q11) * w11;
    float2 fp; fp.x = f0; fp.y = f1;
    __hip_bfloat162 hb = __float22bfloat162_rn(fp);
    union { __hip_bfloat162 h; u32 u; } cv; cv.h = hb;
    return cv.u;
}

// per-(pixel,tap) sampling context; pure VALU to build
struct QC {
    float w00, w01, w10, w11;
    int y0, x0, r00, fast;
};

static __device__ __forceinline__ QC qc_make(int tap, int h, int w,
                                             float dy, float dx, float mk,
                                             int hy0, int hx0)
{
    QC t;
    float py = (float)(h + tap / 3 - 1) + dy;
    float px = (float)(w + tap % 3 - 1) + dx;
    float fy = floorf(py), fx = floorf(px);
    float wy = py - fy, wx = px - fx;
    int y0 = (int)fy, x0 = (int)fx;
    int y1 = y0 + 1, x1 = x0 + 1;
    float w00 = (1.f - wy) * (1.f - wx) * mk;
    float w01 = (1.f - wy) * wx * mk;
    float w10 = wy * (1.f - wx) * mk;
    float w11 = wy * wx * mk;
    if (y0 < 0 || y0 >= H_) { w00 = 0.f; w01 = 0.f; }
    if (y1 < 0 || y1 >= H_) { w10 = 0.f; w11 = 0.f; }
    if (x0 < 0 || x0 >= W_) { w00 = 0.f; w10 = 0.f; }
    if (x1 < 0 || x1 >= W_) { w01 = 0.f; w11 = 0.f; }
    t.w00 = w00; t.w01 = w01; t.w10 = w10; t.w11 = w11;
    t.y0 = y0; t.x0 = x0;
    t.fast = (y0 >= hy0) && (y0 <= hy0 + 14) && (x0 >= hx0) && (x0 <= hx0 + 14);
    t.r00 = (y0 - hy0) * 16 + (x0 - hx0);
    return t;
}

// read 4 bilinear sources (LDS halo fast path / global slow path) and blend
// into 2 packed 16B chunks for this thread (chunks k and k+8 of 16).
static __device__ __forceinline__ void qblend(const QC& c, int k, int cH,
                                              const u16* Hl, size_t rbimg,
                                              const u16* __restrict__ xT,
                                              u32x4 ov[2])
{
    const char* Hb = (const char*)Hl;
    const u16 *b00 = nullptr, *b01 = nullptr, *b10 = nullptr, *b11 = nullptr;
    if (!c.fast){
        int cy0 = min(max(c.y0, 0), H_ - 1), cy1 = min(max(c.y0 + 1, 0), H_ - 1);
        int cx0 = min(max(c.x0, 0), W_ - 1), cx1 = min(max(c.x0 + 1, 0), W_ - 1);
        const u16* base = xT + rbimg + cH * 128;
        b00 = base + ((size_t)cy0 * W_ + cx0) * C_;
        b01 = base + ((size_t)cy0 * W_ + cx1) * C_;
        b10 = base + ((size_t)cy1 * W_ + cx0) * C_;
        b11 = base + ((size_t)cy1 * W_ + cx1) * C_;
    }
    int r00 = c.r00, r01 = c.r00 + 1, r10 = c.r00 + 16, r11 = c.r00 + 17;
    #pragma unroll
    for (int i = 0; i < 2; ++i){
        int ck = k + 8 * i;
        u32x4 q00, q01, q10, q11;
        if (c.fast){
            q00 = *(const u32x4*)(Hb + r00 * 256 + ((ck ^ (r00 & 15)) << 4));
            q01 = *(const u32x4*)(Hb + r01 * 256 + ((ck ^ (r01 & 15)) << 4));
            q10 = *(const u32x4*)(Hb + r10 * 256 + ((ck ^ (r10 & 15)) << 4));
            q11 = *(const u32x4*)(Hb + r11 * 256 + ((ck ^ (r11 & 15)) << 4));
        } else {
            int cc = ck * 8;
            q00 = *(const u32x4*)(b00 + cc);
            q01 = *(const u32x4*)(b01 + cc);
            q10 = *(const u32x4*)(b10 + cc);
            q11 = *(const u32x4*)(b11 + cc);
        }
        #pragma unroll
        for (int j = 0; j < 4; ++j)
            ov[i][j] = blerp_pack(q00[j], q01[j], q10[j], q11[j],
                                  c.w00, c.w01, c.w10, c.w11);
    }
}

// ---------------------------------------------------------------------------
// Kernel 1: transpose x [B,C,H,W] f32 -> xT [B,H,W,C] bf16
// ---------------------------------------------------------------------------
__global__ __launch_bounds__(256) void transpose_x(const float* __restrict__ x,
                                                   u16* __restrict__ xT)
{
    __shared__ float t[32][33];
    int tid = threadIdx.x;
    int tx = tid & 31, ty = tid >> 5;          // 32 x 8
    int bi = blockIdx.x;
    int w0 = (bi % 3) * 32;
    int c0 = ((bi / 3) % 8) * 32;
    int bh = bi / 24;                           // b*H + h  (0..383)
    int b = bh / H_, h = bh - b * H_;
    #pragma unroll
    for (int r = 0; r < 4; ++r){
        int c = c0 + ty + r * 8;
        t[ty + r * 8][tx] = x[(size_t)(b * C_ + c) * HW_ + h * W_ + w0 + tx];
    }
    __syncthreads();
    #pragma unroll
    for (int r = 0; r < 4; ++r){
        int w = w0 + ty + r * 8;
        xT[((size_t)(b * H_ + h) * W_ + w) * C_ + c0 + tx] = f2bf(t[tx][ty + r * 8]);
    }
}

// ---------------------------------------------------------------------------
// Kernel 2: pack weight [O,C,3,3] f32 -> W3 bf16:
//   kidx = tap*256 + c ; flat u16 index = (kidx>>3)*2048 + o*8 + (kidx&7)
// ---------------------------------------------------------------------------
__global__ __launch_bounds__(256) void pack_w(const float* __restrict__ wt,
                                              u16* __restrict__ w3)
{
    int n = blockIdx.x * 256 + threadIdx.x;     // < 589824 = 256*256*9
    int o = n / 2304;
    int rem = n - o * 2304;
    int c = rem / 9;
    int tap = rem - c * 9;
    int kidx = tap * 256 + c;
    w3[(size_t)(kidx >> 3) * 2048 + o * 8 + (kidx & 7)] = f2bf(wt[n]);
}

// ---------------------------------------------------------------------------
// Kernel 3: deformable-conv implicit GEMM with LDS halo, blend overlapped
// with MFMA. 576 blocks x 512 threads (8 waves); block = 8x8 patch;
// XCD-contiguous tile = (bid&7)*72 + bid>>3.
// Per 128-ch half: stage 16x16-row halo (64 KB, coalesced, 9-tap reuse:
// gather L2 traffic 680 -> 74 MB). Hl is STABLE across the 9 taps, so the
// next tap's 8 Hl reads + blerp run inside the current tap's MFMA region;
// the write phase is just 2 ds_write_b128. off/msk rotate 2 taps ahead so
// tap setup is pure VALU. Out-of-halo samples (~2e-4) take a global slow
// path with exact reference clamping. LDS 80 KB -> 2 blocks/CU.
// ---------------------------------------------------------------------------
__global__ __launch_bounds__(512) void dcn_main(
    const float* __restrict__ off, const float* __restrict__ msk,
    const u16* __restrict__ xT, const u16* __restrict__ w3,
    float* __restrict__ convOut, float* __restrict__ stats)
{
    __shared__ u16 Hl[256 * 128];   // 64 KB halo, rows of 256B, chunk-swz
    __shared__ u16 At[64 * 128];    // 16 KB A-tile, rows of 256B, chunk-swz

    int tid = threadIdx.x;
    int lane = tid & 63;
    int wv = tid >> 6;               // 0..7 : 32-col chunk
    int l15 = lane & 15;
    int g = lane >> 4;               // 0..3

    int bid = blockIdx.x;
    int tile = (bid & 7) * 72 + (bid >> 3);     // 576 = 8*72, bijective
    int b = tile / 144;
    int t = tile - b * 144;
    int ty_ = t / 12, tx_ = t - ty_ * 12;
    int py0 = ty_ * 8, px0 = tx_ * 8;

    f32x4 acc[4][2];
    #pragma unroll
    for (int i = 0; i < 4; ++i)
        #pragma unroll
        for (int q = 0; q < 2; ++q)
            acc[i][q] = (f32x4){0.f, 0.f, 0.f, 0.f};

    // blend assignment: 8 threads per pixel, chunks k and k+8
    int p = tid >> 3;                // pixel 0..63 within patch
    int k = tid & 7;
    int h = py0 + (p >> 3);
    int w = px0 + (p & 7);
    int hw = h * W_ + w;
    size_t offb = (size_t)b * 18 * HW_ + hw;
    size_t mskb = (size_t)b * 9 * HW_ + hw;
    int hy0 = py0 - 4, hx0 = px0 - 4;
    size_t rbimg = (size_t)b * HW_ * C_;

    for (int cH = 0; cH < 2; ++cH){
        // off/msk for taps 0 and 1 (L2-hot on second half)
        float cdy = off[offb];
        float cdx = off[offb + HW_];
        float cmk = msk[mskb];
        float ndy = off[offb + 2 * HW_];
        float ndx = off[offb + 3 * HW_];
        float nmk = msk[mskb + HW_];
        // ---- stage halo (coalesced; clamped at image edges) ----
        #pragma unroll
        for (int it = 0; it < 8; ++it){
            int u = it * 512 + tid;          // (row 0..255, 16B-chunk 0..15)
            int row = u >> 4, ck = u & 15;
            int gy = min(max(hy0 + (row >> 4), 0), H_ - 1);
            int gx = min(max(hx0 + (row & 15), 0), W_ - 1);
            u32x4 v = *(const u32x4*)(xT + rbimg + ((size_t)gy * W_ + gx) * C_
                                      + cH * 128 + ck * 8);
            *(u32x4*)((char*)Hl + row * 256 + ((ck ^ (row & 15)) << 4)) = v;
        }
        __syncthreads();

        // prologue blend for tap 0
        QC c = qc_make(0, h, w, cdy, cdx, cmk, hy0, hx0);
        u32x4 ov[2];
        qblend(c, k, cH, Hl, rbimg, xT, ov);

        for (int tap = 0; tap < 9; ++tap){
            // ---- write phase: commit blended chunks to At ----
            #pragma unroll
            for (int i = 0; i < 2; ++i){
                int ck = k + 8 * i;
                *(u32x4*)((char*)At + p * 256 + ((ck ^ (p & 15)) << 4)) = ov[i];
            }
            __syncthreads();   // At ready

            // ---- MFMA region: 4 K-steps + next tap's blend overlapped ----
            if (tap < 8){
                c = qc_make(tap + 1, h, w, ndy, ndx, nmk, hy0, hx0);
                qblend(c, k, cH, Hl, rbimg, xT, ov);
                if (tap < 7){
                    ndy = off[offb + (size_t)(2 * tap + 4) * HW_];
                    ndx = off[offb + (size_t)(2 * tap + 5) * HW_];
                    nmk = msk[mskb + (size_t)(tap + 2) * HW_];
                }
            }
            __builtin_amdgcn_s_setprio(1);
            #pragma unroll
            for (int s = 0; s < 4; ++s){
                int ck = s * 4 + g;
                s16x8 a[4];
                #pragma unroll
                for (int i = 0; i < 4; ++i){
                    int r = i * 16 + l15;
                    a[i] = *(const s16x8*)((const char*)At + r * 256
                                           + ((ck ^ (r & 15)) << 4));
                }
                const u16* wrow = w3 + (size_t)(tap * 32 + cH * 16 + s * 4 + g) * 2048
                                + (size_t)(wv * 32 + l15) * 8;
                s16x8 b0 = *(const s16x8*)(wrow);
                s16x8 b1 = *(const s16x8*)(wrow + 128);
                #pragma unroll
                for (int i = 0; i < 4; ++i){
                    acc[i][0] = __builtin_amdgcn_mfma_f32_16x16x32_bf16(a[i], b0, acc[i][0], 0, 0, 0);
                    acc[i][1] = __builtin_amdgcn_mfma_f32_16x16x32_bf16(a[i], b1, acc[i][1], 0, 0, 0);
                }
            }
            __builtin_amdgcn_s_setprio(0);
            __syncthreads();   // At consumed (next write / halo restage safe)
        }
    }

    // ---- epilogue: store conv f32 at global [m][o], accumulate GN stats ----
    float s0 = 0.f, s20 = 0.f;
    size_t mbase = (size_t)b * HW_;
    #pragma unroll
    for (int i = 0; i < 4; ++i){
        #pragma unroll
        for (int q = 0; q < 2; ++q){
            int oc = wv * 32 + q * 16 + l15;
            #pragma unroll
            for (int j = 0; j < 4; ++j){
                float v = acc[i][q][j];
                int pp = i * 16 + g * 4 + j;              // pixel in patch
                int mr_hw = (py0 + (pp >> 3)) * W_ + px0 + (pp & 7);
                convOut[(mbase + mr_hw) * 256 + oc] = v;
                s0 += v; s20 += v * v;
            }
        }
    }
    #pragma unroll
    for (int d = 32; d; d >>= 1){
        s0  += __shfl_xor(s0, d, 64);
        s20 += __shfl_xor(s20, d, 64);
    }
    if (lane == 0){
        atomicAdd(&stats[(b * 8 + wv) * 2 + 0], s0);
        atomicAdd(&stats[(b * 8 + wv) * 2 + 1], s20);
    }
}

// ---------------------------------------------------------------------------
// Kernel 4: GroupNorm(8) + ReLU, transposing [m][o] -> [b,o,h,w]
// ---------------------------------------------------------------------------
__global__ __launch_bounds__(256) void gn_final(
    const float* __restrict__ convOut, const float* __restrict__ stats,
    const float* __restrict__ gamma, const float* __restrict__ beta,
    float* __restrict__ out)
{
    __shared__ float t[64][257];
    int tid = threadIdx.x;
    int m0 = blockIdx.x * 64;
    int b = m0 / HW_;
    const f32x4* src = (const f32x4*)(convOut + (size_t)m0 * 256);
    #pragma unroll
    for (int it = 0; it < 16; ++it){
        int idx = it * 256 + tid;
        int r = idx >> 6;
        int c4 = idx & 63;
        f32x4 v = src[(size_t)r * 64 + c4];
        t[r][c4 * 4 + 0] = v[0];
        t[r][c4 * 4 + 1] = v[1];
        t[r][c4 * 4 + 2] = v[2];
        t[r][c4 * 4 + 3] = v[3];
    }
    __syncthreads();
    int lanem = tid & 63;
    int hw = (m0 - b * HW_) + lanem;
    float* dst = out + (size_t)b * O_ * HW_ + hw;
    const float invN = 1.f / 294912.f;   // 32 ch * 9216 px
    #pragma unroll 8
    for (int it = 0; it < 64; ++it){
        int o = it * 4 + (tid >> 6);
        int gidx = (b * 8 + (o >> 5)) * 2;
        float sm = stats[gidx + 0];
        float sq = stats[gidx + 1];
        float mu = sm * invN;
        float var = sq * invN - mu * mu;
        float inv = rsqrtf(var + 1e-5f);
        float sc = gamma[o] * inv;
        float sh = beta[o] - mu * sc;
        float v = t[lanem][o];
        dst[(size_t)o * HW_] = fmaxf(v * sc + sh, 0.f);
    }
}

// ---------------------------------------------------------------------------
extern "C" void kernel_launch(void* const* d_in, const int* in_sizes, int n_in,
                              void* d_out, int out_size, void* d_ws, size_t ws_size,
                              hipStream_t stream)
{
    const float* x     = (const float*)d_in[0];
    const float* off   = (const float*)d_in[1];
    const float* msk   = (const float*)d_in[2];
    const float* wt    = (const float*)d_in[3];
    const float* gamma = (const float*)d_in[4];
    const float* beta  = (const float*)d_in[5];
    float* out = (float*)d_out;

    char* ws = (char*)d_ws;
    u16*   xT      = (u16*)ws;                       // 18,874,368 B
    u16*   w3      = (u16*)(ws + 18874368);          //  1,179,648 B
    float* convOut = (float*)(ws + 20054016);        // 37,748,736 B
    float* stats   = (float*)(ws + 57802752);        //        256 B

    hipMemsetAsync(stats, 0, 256, stream);
    hipLaunchKernelGGL(transpose_x, dim3(9216), dim3(256), 0, stream, x, xT);
    hipLaunchKernelGGL(pack_w,      dim3(2304), dim3(256), 0, stream, wt, w3);
    hipLaunchKernelGGL(dcn_main,    dim3(576),  dim3(512), 0, stream,
                       off, msk, xT, w3, convOut, stats);
    hipLaunchKernelGGL(gn_final,    dim3(576),  dim3(256), 0, stream,
                       convOut, stats, gamma, beta, out);
}

// Round 12
// 206.466 us; speedup vs baseline: 1.0910x; 1.0910x over previous
//
#include <hip/hip_runtime.h>
#include <hip/hip_bf16.h>
#include <stdint.h>

typedef __attribute__((ext_vector_type(4))) float f32x4;
typedef __attribute__((ext_vector_type(8))) short s16x8;
typedef __attribute__((ext_vector_type(4))) unsigned int u32x4;
typedef unsigned short u16;
typedef unsigned int u32;

#define B_ 4
#define C_ 256
#define O_ 256
#define H_ 96
#define W_ 96
#define HW_ (H_*W_)      /* 9216 */
#define M_ (B_*HW_)      /* 36864 */

static __device__ __forceinline__ float asf(u32 u){
    union { u32 u; float f; } x; x.u = u; return x.f;
}
static __device__ __forceinline__ u16 f2bf(float f){
    union { float f; u32 u; } x; x.f = f;
    u32 u = x.u;
    u32 r = (u + 0x7fffu + ((u >> 16) & 1u)) >> 16;
    return (u16)r;
}
// bilinear-combine a bf16 pair (packed in u32) from 4 source pairs, repack
static __device__ __forceinline__ u32 blerp_pack(u32 q00, u32 q01, u32 q10, u32 q11,
                                                 float w00, float w01, float w10, float w11)
{
    float f0 = asf(q00 << 16) * w00 + asf(q01 << 16) * w01
             + asf(q10 << 16) * w10 + asf(q11 << 16) * w11;
    float f1 = asf(q00) * w00 + asf(q01) * w01 + asf(q10) * w10 + asf(q11) * w11;
    float2 fp; fp.x = f0; fp.y = f1;
    __hip_bfloat162 hb = __float22bfloat162_rn(fp);
    union { __hip_bfloat162 h; u32 u; } cv; cv.h = hb;
    return cv.u;
}

struct TapCtx {
    float w00, w01, w10, w11;
    const u16 *r00, *r01, *r10, *r11;
};

static __device__ __forceinline__ TapCtx tap_setup(
    int tap, int b, int h, int w, int hw,
    const float* __restrict__ off, const float* __restrict__ msk,
    const u16* __restrict__ xT)
{
    TapCtx t;
    float dy = off[(size_t)(b * 18 + 2 * tap) * HW_ + hw];
    float dx = off[(size_t)(b * 18 + 2 * tap + 1) * HW_ + hw];
    float mk = msk[(size_t)(b * 9 + tap) * HW_ + hw];
    float py = (float)(h + tap / 3 - 1) + dy;
    float px = (float)(w + tap % 3 - 1) + dx;
    float fy = floorf(py), fx = floorf(px);
    float wy = py - fy, wx = px - fx;
    int y0 = (int)fy, x0 = (int)fx;
    int y1 = y0 + 1, x1 = x0 + 1;
    float w00 = (1.f - wy) * (1.f - wx) * mk;
    float w01 = (1.f - wy) * wx * mk;
    float w10 = wy * (1.f - wx) * mk;
    float w11 = wy * wx * mk;
    if (y0 < 0 || y0 >= H_) { w00 = 0.f; w01 = 0.f; }
    if (y1 < 0 || y1 >= H_) { w10 = 0.f; w11 = 0.f; }
    if (x0 < 0 || x0 >= W_) { w00 = 0.f; w10 = 0.f; }
    if (x1 < 0 || x1 >= W_) { w01 = 0.f; w11 = 0.f; }
    int cy0 = min(max(y0, 0), H_ - 1), cy1 = min(max(y1, 0), H_ - 1);
    int cx0 = min(max(x0, 0), W_ - 1), cx1 = min(max(x1, 0), W_ - 1);
    size_t rb = (size_t)b * HW_ * C_;
    t.r00 = xT + rb + ((size_t)cy0 * W_ + cx0) * C_;
    t.r01 = xT + rb + ((size_t)cy0 * W_ + cx1) * C_;
    t.r10 = xT + rb + ((size_t)cy1 * W_ + cx0) * C_;
    t.r11 = xT + rb + ((size_t)cy1 * W_ + cx1) * C_;
    t.w00 = w00; t.w01 = w01; t.w10 = w10; t.w11 = w11;
    return t;
}

// ---------------------------------------------------------------------------
// Kernel 1: transpose x [B,C,H,W] f32 -> xT [B,H,W,C] bf16
// ---------------------------------------------------------------------------
__global__ __launch_bounds__(256) void transpose_x(const float* __restrict__ x,
                                                   u16* __restrict__ xT)
{
    __shared__ float t[32][33];
    int tid = threadIdx.x;
    int tx = tid & 31, ty = tid >> 5;          // 32 x 8
    int bi = blockIdx.x;
    int w0 = (bi % 3) * 32;
    int c0 = ((bi / 3) % 8) * 32;
    int bh = bi / 24;                           // b*H + h  (0..383)
    int b = bh / H_, h = bh - b * H_;
    #pragma unroll
    for (int r = 0; r < 4; ++r){
        int c = c0 + ty + r * 8;
        t[ty + r * 8][tx] = x[(size_t)(b * C_ + c) * HW_ + h * W_ + w0 + tx];
    }
    __syncthreads();
    #pragma unroll
    for (int r = 0; r < 4; ++r){
        int w = w0 + ty + r * 8;
        xT[((size_t)(b * H_ + h) * W_ + w) * C_ + c0 + tx] = f2bf(t[tx][ty + r * 8]);
    }
}

// ---------------------------------------------------------------------------
// Kernel 2: pack weight [O,C,3,3] f32 -> W3 bf16:
//   kidx = tap*256 + c ; flat u16 index = (kidx>>3)*2048 + o*8 + (kidx&7)
// ---------------------------------------------------------------------------
__global__ __launch_bounds__(256) void pack_w(const float* __restrict__ wt,
                                              u16* __restrict__ w3)
{
    int n = blockIdx.x * 256 + threadIdx.x;     // < 589824 = 256*256*9
    int o = n / 2304;
    int rem = n - o * 2304;
    int c = rem / 9;
    int tap = rem - c * 9;
    int kidx = tap * 256 + c;
    w3[(size_t)(kidx >> 3) * 2048 + o * 8 + (kidx & 7)] = f2bf(wt[n]);
}

// ---------------------------------------------------------------------------
// Kernel 3: deformable-conv implicit GEMM, software-pipelined (R8 structure,
// spill removed). 576 blocks x 512 threads (8 waves). Block = 8x8 patch,
// BM=64, BN=256; wave wv owns cols [wv*32, wv*32+32) (acc[4][2]).
// XCD-contiguous tiles. Double-buffered 2x32KB A-tile: per tap, issue next
// tap's scattered gather loads (2 rounds of 8x16B) around the two 4-step
// MFMA clusters; ONE barrier per tap. Plain launch_bounds(512): compiler
// allocates enough VGPR for acc+staging (R8's (512,4) clamped to 64 VGPR and
// spilled ~15 MB of scratch traffic per dispatch).
// ---------------------------------------------------------------------------
__global__ __launch_bounds__(512) void dcn_main(
    const float* __restrict__ off, const float* __restrict__ msk,
    const u16* __restrict__ xT, const u16* __restrict__ w3,
    float* __restrict__ convOut, float* __restrict__ stats)
{
    __shared__ u16 At[2][64 * 256];  // 2 x 32 KB, rows 512B, 16B-chunk swz
    int tid = threadIdx.x;
    int lane = tid & 63;
    int wv = tid >> 6;               // 0..7 : 32-col chunk
    int l15 = lane & 15;
    int g = lane >> 4;               // 0..3

    int bid = blockIdx.x;
    int tile = (bid & 7) * 72 + (bid >> 3);     // 576 = 8*72, bijective
    int b = tile / 144;
    int t = tile - b * 144;
    int ty_ = t / 12, tx_ = t - ty_ * 12;
    int py0 = ty_ * 8, px0 = tx_ * 8;

    f32x4 acc[4][2];
    #pragma unroll
    for (int i = 0; i < 4; ++i)
        #pragma unroll
        for (int q = 0; q < 2; ++q)
            acc[i][q] = (f32x4){0.f, 0.f, 0.f, 0.f};

    // gather assignment: 8 threads per pixel, 4 chunks each (k,k+8,k+16,k+24)
    int p = tid >> 3;                // pixel 0..63 within patch
    int k = tid & 7;
    int h = py0 + (p >> 3);
    int w = px0 + (p & 7);
    int hw = h * W_ + w;

    // ---- prologue: gather tap 0 into At[0] ----
    {
        TapCtx tp = tap_setup(0, b, h, w, hw, off, msk, xT);
        #pragma unroll
        for (int i = 0; i < 4; ++i){
            int ck = k + i * 8;
            int c = ck * 8;
            u32x4 q00 = *(const u32x4*)(tp.r00 + c);
            u32x4 q01 = *(const u32x4*)(tp.r01 + c);
            u32x4 q10 = *(const u32x4*)(tp.r10 + c);
            u32x4 q11 = *(const u32x4*)(tp.r11 + c);
            u32x4 outv;
            #pragma unroll
            for (int j = 0; j < 4; ++j)
                outv[j] = blerp_pack(q00[j], q01[j], q10[j], q11[j],
                                     tp.w00, tp.w01, tp.w10, tp.w11);
            u32 boff = (u32)(p * 512) + (u32)((ck ^ (p & 15)) << 4);
            *(u32x4*)((char*)&At[0][0] + boff) = outv;
        }
    }
    __syncthreads();

    int cur = 0;
    for (int tap = 0; tap < 9; ++tap){
        bool pre = (tap < 8);
        TapCtx tn;
        u32x4 s00[2], s01[2], s10[2], s11[2];
        if (pre){
            tn = tap_setup(tap + 1, b, h, w, hw, off, msk, xT);
            #pragma unroll
            for (int i = 0; i < 2; ++i){           // round 1: chunks k, k+8
                int c = (k + i * 8) * 8;
                s00[i] = *(const u32x4*)(tn.r00 + c);
                s01[i] = *(const u32x4*)(tn.r01 + c);
                s10[i] = *(const u32x4*)(tn.r10 + c);
                s11[i] = *(const u32x4*)(tn.r11 + c);
            }
        }
        const char* Ac = (const char*)&At[cur][0];
        char* An = (char*)&At[cur ^ 1][0];

        // ---- MFMA steps 0..3 (chunks 0..15 of At[cur]) ----
        __builtin_amdgcn_s_setprio(1);
        #pragma unroll
        for (int step = 0; step < 4; ++step){
            int ck = step * 4 + g;
            s16x8 a[4];
            #pragma unroll
            for (int i = 0; i < 4; ++i){
                int r = i * 16 + l15;
                u32 boff = (u32)(r * 512) + (u32)((ck ^ (r & 15)) << 4);
                a[i] = *(const s16x8*)(Ac + boff);
            }
            const u16* wrow = w3 + (size_t)(tap * 32 + step * 4 + g) * 2048
                            + (size_t)(wv * 32 + l15) * 8;
            s16x8 b0 = *(const s16x8*)(wrow);
            s16x8 b1 = *(const s16x8*)(wrow + 128);
            #pragma unroll
            for (int i = 0; i < 4; ++i){
                acc[i][0] = __builtin_amdgcn_mfma_f32_16x16x32_bf16(a[i], b0, acc[i][0], 0, 0, 0);
                acc[i][1] = __builtin_amdgcn_mfma_f32_16x16x32_bf16(a[i], b1, acc[i][1], 0, 0, 0);
            }
        }
        __builtin_amdgcn_s_setprio(0);

        if (pre){
            // blend+write round 1, then issue round 2 (chunks k+16, k+24)
            #pragma unroll
            for (int i = 0; i < 2; ++i){
                int ck = k + i * 8;
                u32x4 outv;
                #pragma unroll
                for (int j = 0; j < 4; ++j)
                    outv[j] = blerp_pack(s00[i][j], s01[i][j], s10[i][j], s11[i][j],
                                         tn.w00, tn.w01, tn.w10, tn.w11);
                u32 boff = (u32)(p * 512) + (u32)((ck ^ (p & 15)) << 4);
                *(u32x4*)(An + boff) = outv;
            }
            #pragma unroll
            for (int i = 0; i < 2; ++i){
                int c = (k + 16 + i * 8) * 8;
                s00[i] = *(const u32x4*)(tn.r00 + c);
                s01[i] = *(const u32x4*)(tn.r01 + c);
                s10[i] = *(const u32x4*)(tn.r10 + c);
                s11[i] = *(const u32x4*)(tn.r11 + c);
            }
        }

        // ---- MFMA steps 4..7 (chunks 16..31 of At[cur]) ----
        __builtin_amdgcn_s_setprio(1);
        #pragma unroll
        for (int step = 4; step < 8; ++step){
            int ck = step * 4 + g;
            s16x8 a[4];
            #pragma unroll
            for (int i = 0; i < 4; ++i){
                int r = i * 16 + l15;
                u32 boff = (u32)(r * 512) + (u32)((ck ^ (r & 15)) << 4);
                a[i] = *(const s16x8*)(Ac + boff);
            }
            const u16* wrow = w3 + (size_t)(tap * 32 + step * 4 + g) * 2048
                            + (size_t)(wv * 32 + l15) * 8;
            s16x8 b0 = *(const s16x8*)(wrow);
            s16x8 b1 = *(const s16x8*)(wrow + 128);
            #pragma unroll
            for (int i = 0; i < 4; ++i){
                acc[i][0] = __builtin_amdgcn_mfma_f32_16x16x32_bf16(a[i], b0, acc[i][0], 0, 0, 0);
                acc[i][1] = __builtin_amdgcn_mfma_f32_16x16x32_bf16(a[i], b1, acc[i][1], 0, 0, 0);
            }
        }
        __builtin_amdgcn_s_setprio(0);

        if (pre){
            #pragma unroll
            for (int i = 0; i < 2; ++i){
                int ck = k + 16 + i * 8;
                u32x4 outv;
                #pragma unroll
                for (int j = 0; j < 4; ++j)
                    outv[j] = blerp_pack(s00[i][j], s01[i][j], s10[i][j], s11[i][j],
                                         tn.w00, tn.w01, tn.w10, tn.w11);
                u32 boff = (u32)(p * 512) + (u32)((ck ^ (p & 15)) << 4);
                *(u32x4*)(An + boff) = outv;
            }
        }
        __syncthreads();
        cur ^= 1;
    }

    // ---- epilogue: store conv f32 at global [m][o], accumulate GN stats ----
    float s0 = 0.f, s20 = 0.f;
    size_t mbase = (size_t)b * HW_;
    #pragma unroll
    for (int i = 0; i < 4; ++i){
        #pragma unroll
        for (int q = 0; q < 2; ++q){
            int oc = wv * 32 + q * 16 + l15;
            #pragma unroll
            for (int j = 0; j < 4; ++j){
                float v = acc[i][q][j];
                int pp = i * 16 + g * 4 + j;              // pixel in patch
                int mr_hw = (py0 + (pp >> 3)) * W_ + px0 + (pp & 7);
                convOut[(mbase + mr_hw) * 256 + oc] = v;
                s0 += v; s20 += v * v;
            }
        }
    }
    #pragma unroll
    for (int d = 32; d; d >>= 1){
        s0  += __shfl_xor(s0, d, 64);
        s20 += __shfl_xor(s20, d, 64);
    }
    if (lane == 0){
        atomicAdd(&stats[(b * 8 + wv) * 2 + 0], s0);
        atomicAdd(&stats[(b * 8 + wv) * 2 + 1], s20);
    }
}

// ---------------------------------------------------------------------------
// Kernel 4: GroupNorm(8) + ReLU, transposing [m][o] -> [b,o,h,w]
// ---------------------------------------------------------------------------
__global__ __launch_bounds__(256) void gn_final(
    const float* __restrict__ convOut, const float* __restrict__ stats,
    const float* __restrict__ gamma, const float* __restrict__ beta,
    float* __restrict__ out)
{
    __shared__ float t[64][257];
    int tid = threadIdx.x;
    int m0 = blockIdx.x * 64;
    int b = m0 / HW_;
    const f32x4* src = (const f32x4*)(convOut + (size_t)m0 * 256);
    #pragma unroll
    for (int it = 0; it < 16; ++it){
        int idx = it * 256 + tid;
        int r = idx >> 6;
        int c4 = idx & 63;
        f32x4 v = src[(size_t)r * 64 + c4];
        t[r][c4 * 4 + 0] = v[0];
        t[r][c4 * 4 + 1] = v[1];
        t[r][c4 * 4 + 2] = v[2];
        t[r][c4 * 4 + 3] = v[3];
    }
    __syncthreads();
    int lanem = tid & 63;
    int hw = (m0 - b * HW_) + lanem;
    float* dst = out + (size_t)b * O_ * HW_ + hw;
    const float invN = 1.f / 294912.f;   // 32 ch * 9216 px
    #pragma unroll 8
    for (int it = 0; it < 64; ++it){
        int o = it * 4 + (tid >> 6);
        int gidx = (b * 8 + (o >> 5)) * 2;
        float sm = stats[gidx + 0];
        float sq = stats[gidx + 1];
        float mu = sm * invN;
        float var = sq * invN - mu * mu;
        float inv = rsqrtf(var + 1e-5f);
        float sc = gamma[o] * inv;
        float sh = beta[o] - mu * sc;
        float v = t[lanem][o];
        dst[(size_t)o * HW_] = fmaxf(v * sc + sh, 0.f);
    }
}

// ---------------------------------------------------------------------------
extern "C" void kernel_launch(void* const* d_in, const int* in_sizes, int n_in,
                              void* d_out, int out_size, void* d_ws, size_t ws_size,
                              hipStream_t stream)
{
    const float* x     = (const float*)d_in[0];
    const float* off   = (const float*)d_in[1];
    const float* msk   = (const float*)d_in[2];
    const float* wt    = (const float*)d_in[3];
    const float* gamma = (const float*)d_in[4];
    const float* beta  = (const float*)d_in[5];
    float* out = (float*)d_out;

    char* ws = (char*)d_ws;
    u16*   xT      = (u16*)ws;                       // 18,874,368 B
    u16*   w3      = (u16*)(ws + 18874368);          //  1,179,648 B
    float* convOut = (float*)(ws + 20054016);        // 37,748,736 B
    float* stats   = (float*)(ws + 57802752);        //        256 B

    hipMemsetAsync(stats, 0, 256, stream);
    hipLaunchKernelGGL(transpose_x, dim3(9216), dim3(256), 0, stream, x, xT);
    hipLaunchKernelGGL(pack_w,      dim3(2304), dim3(256), 0, stream, wt, w3);
    hipLaunchKernelGGL(dcn_main,    dim3(576),  dim3(512), 0, stream,
                       off, msk, xT, w3, convOut, stats);
    hipLaunchKernelGGL(gn_final,    dim3(576),  dim3(256), 0, stream,
                       convOut, stats, gamma, beta, out);
}

// Round 13
// 171.175 us; speedup vs baseline: 1.3159x; 1.2062x over previous
//
#include <hip/hip_runtime.h>
#include <hip/hip_bf16.h>
#include <stdint.h>

typedef __attribute__((ext_vector_type(4))) float f32x4;
typedef __attribute__((ext_vector_type(8))) short s16x8;
typedef __attribute__((ext_vector_type(4))) unsigned int u32x4;
typedef unsigned short u16;
typedef unsigned int u32;

#define B_ 4
#define C_ 256
#define O_ 256
#define H_ 96
#define W_ 96
#define HW_ (H_*W_)      /* 9216 */
#define M_ (B_*HW_)      /* 36864 */

static __device__ __forceinline__ float asf(u32 u){
    union { u32 u; float f; } x; x.u = u; return x.f;
}
static __device__ __forceinline__ u16 f2bf(float f){
    union { float f; u32 u; } x; x.f = f;
    u32 u = x.u;
    u32 r = (u + 0x7fffu + ((u >> 16) & 1u)) >> 16;
    return (u16)r;
}
// bilinear-combine a bf16 pair (packed in u32) from 4 source pairs, repack
static __device__ __forceinline__ u32 blerp_pack(u32 q00, u32 q01, u32 q10, u32 q11,
                                                 float w00, float w01, float w10, float w11)
{
    float f0 = asf(q00 << 16) * w00 + asf(q01 << 16) * w01
             + asf(q10 << 16) * w10 + asf(q11 << 16) * w11;
    float f1 = asf(q00) * w00 + asf(q01) * w01 + asf(q10) * w10 + asf(q11) * w11;
    float2 fp; fp.x = f0; fp.y = f1;
    __hip_bfloat162 hb = __float22bfloat162_rn(fp);
    union { __hip_bfloat162 h; u32 u; } cv; cv.h = hb;
    return cv.u;
}

// compact tap context: 4 weights + 4 x 32-bit element offsets into xT
struct TapCtx {
    float w00, w01, w10, w11;
    u32 o00, o01, o10, o11;
};

static __device__ __forceinline__ TapCtx tap_setup(
    int tap, int b, int h, int w, int hw,
    const float* __restrict__ off, const float* __restrict__ msk)
{
    TapCtx t;
    float dy = off[(size_t)(b * 18 + 2 * tap) * HW_ + hw];
    float dx = off[(size_t)(b * 18 + 2 * tap + 1) * HW_ + hw];
    float mk = msk[(size_t)(b * 9 + tap) * HW_ + hw];
    float py = (float)(h + tap / 3 - 1) + dy;
    float px = (float)(w + tap % 3 - 1) + dx;
    float fy = floorf(py), fx = floorf(px);
    float wy = py - fy, wx = px - fx;
    int y0 = (int)fy, x0 = (int)fx;
    int y1 = y0 + 1, x1 = x0 + 1;
    float w00 = (1.f - wy) * (1.f - wx) * mk;
    float w01 = (1.f - wy) * wx * mk;
    float w10 = wy * (1.f - wx) * mk;
    float w11 = wy * wx * mk;
    if (y0 < 0 || y0 >= H_) { w00 = 0.f; w01 = 0.f; }
    if (y1 < 0 || y1 >= H_) { w10 = 0.f; w11 = 0.f; }
    if (x0 < 0 || x0 >= W_) { w00 = 0.f; w10 = 0.f; }
    if (x1 < 0 || x1 >= W_) { w01 = 0.f; w11 = 0.f; }
    int cy0 = min(max(y0, 0), H_ - 1), cy1 = min(max(y1, 0), H_ - 1);
    int cx0 = min(max(x0, 0), W_ - 1), cx1 = min(max(x1, 0), W_ - 1);
    u32 rb = (u32)b * (u32)(HW_ * C_);
    t.o00 = rb + ((u32)(cy0 * W_ + cx0)) * C_;
    t.o01 = rb + ((u32)(cy0 * W_ + cx1)) * C_;
    t.o10 = rb + ((u32)(cy1 * W_ + cx0)) * C_;
    t.o11 = rb + ((u32)(cy1 * W_ + cx1)) * C_;
    t.w00 = w00; t.w01 = w01; t.w10 = w10; t.w11 = w11;
    return t;
}

// ---------------------------------------------------------------------------
// Kernel 1: transpose x [B,C,H,W] f32 -> xT [B,H,W,C] bf16
// ---------------------------------------------------------------------------
__global__ __launch_bounds__(256) void transpose_x(const float* __restrict__ x,
                                                   u16* __restrict__ xT)
{
    __shared__ float t[32][33];
    int tid = threadIdx.x;
    int tx = tid & 31, ty = tid >> 5;          // 32 x 8
    int bi = blockIdx.x;
    int w0 = (bi % 3) * 32;
    int c0 = ((bi / 3) % 8) * 32;
    int bh = bi / 24;                           // b*H + h  (0..383)
    int b = bh / H_, h = bh - b * H_;
    #pragma unroll
    for (int r = 0; r < 4; ++r){
        int c = c0 + ty + r * 8;
        t[ty + r * 8][tx] = x[(size_t)(b * C_ + c) * HW_ + h * W_ + w0 + tx];
    }
    __syncthreads();
    #pragma unroll
    for (int r = 0; r < 4; ++r){
        int w = w0 + ty + r * 8;
        xT[((size_t)(b * H_ + h) * W_ + w) * C_ + c0 + tx] = f2bf(t[tx][ty + r * 8]);
    }
}

// ---------------------------------------------------------------------------
// Kernel 2: pack weight [O,C,3,3] f32 -> W3 bf16:
//   kidx = tap*256 + c ; flat u16 index = (kidx>>3)*2048 + o*8 + (kidx&7)
// ---------------------------------------------------------------------------
__global__ __launch_bounds__(256) void pack_w(const float* __restrict__ wt,
                                              u16* __restrict__ w3)
{
    int n = blockIdx.x * 256 + threadIdx.x;     // < 589824 = 256*256*9
    int o = n / 2304;
    int rem = n - o * 2304;
    int c = rem / 9;
    int tap = rem - c * 9;
    int kidx = tap * 256 + c;
    w3[(size_t)(kidx >> 3) * 2048 + o * 8 + (kidx & 7)] = f2bf(wt[n]);
}

// ---------------------------------------------------------------------------
// Kernel 3: deformable-conv implicit GEMM, software-pipelined (R8 structure,
// staging granularity halved to fit the 64-VGPR clamp).
// 576 blocks x 512 threads (8 waves). Block = 8x8 patch, BM=64, BN=256;
// wave wv owns cols [wv*32, wv*32+32) (acc[4][2]). XCD-contiguous tiles.
// Double-buffered 2x32KB A-tile. Per tap: FOUR staged sub-rounds, each a
// single 16B chunk (4 loads, 16 VGPR live) issued before / committed after a
// 2-step MFMA cluster. ONE barrier per tap. __launch_bounds__(512,4): the
// clamped allocation empirically beats plain (512) by ~15% (R8 vs R12 A/B);
// smaller staging + 32-bit gather offsets shrink its spill.
// ---------------------------------------------------------------------------
__global__ __launch_bounds__(512, 4) void dcn_main(
    const float* __restrict__ off, const float* __restrict__ msk,
    const u16* __restrict__ xT, const u16* __restrict__ w3,
    float* __restrict__ convOut, float* __restrict__ stats)
{
    __shared__ u16 At[2][64 * 256];  // 2 x 32 KB, rows 512B, 16B-chunk swz
    int tid = threadIdx.x;
    int lane = tid & 63;
    int wv = tid >> 6;               // 0..7 : 32-col chunk
    int l15 = lane & 15;
    int g = lane >> 4;               // 0..3

    int bid = blockIdx.x;
    int tile = (bid & 7) * 72 + (bid >> 3);     // 576 = 8*72, bijective
    int b = tile / 144;
    int t = tile - b * 144;
    int ty_ = t / 12, tx_ = t - ty_ * 12;
    int py0 = ty_ * 8, px0 = tx_ * 8;

    f32x4 acc[4][2];
    #pragma unroll
    for (int i = 0; i < 4; ++i)
        #pragma unroll
        for (int q = 0; q < 2; ++q)
            acc[i][q] = (f32x4){0.f, 0.f, 0.f, 0.f};

    // gather assignment: 8 threads per pixel, 4 chunks each (k,k+8,k+16,k+24)
    int p = tid >> 3;                // pixel 0..63 within patch
    int k = tid & 7;
    int h = py0 + (p >> 3);
    int w = px0 + (p & 7);
    int hw = h * W_ + w;

    // ---- prologue: gather tap 0 into At[0] ----
    {
        TapCtx tp = tap_setup(0, b, h, w, hw, off, msk);
        #pragma unroll
        for (int i = 0; i < 4; ++i){
            int ck = k + i * 8;
            int c = ck * 8;
            u32x4 q00 = *(const u32x4*)(xT + tp.o00 + c);
            u32x4 q01 = *(const u32x4*)(xT + tp.o01 + c);
            u32x4 q10 = *(const u32x4*)(xT + tp.o10 + c);
            u32x4 q11 = *(const u32x4*)(xT + tp.o11 + c);
            u32x4 outv;
            #pragma unroll
            for (int j = 0; j < 4; ++j)
                outv[j] = blerp_pack(q00[j], q01[j], q10[j], q11[j],
                                     tp.w00, tp.w01, tp.w10, tp.w11);
            u32 boff = (u32)(p * 512) + (u32)((ck ^ (p & 15)) << 4);
            *(u32x4*)((char*)&At[0][0] + boff) = outv;
        }
    }
    __syncthreads();

    int cur = 0;
    for (int tap = 0; tap < 9; ++tap){
        bool pre = (tap < 8);
        TapCtx tn;
        u32x4 s00, s01, s10, s11;
        if (pre){
            tn = tap_setup(tap + 1, b, h, w, hw, off, msk);
            int c = k * 8;                         // sub-round 0: chunk k
            s00 = *(const u32x4*)(xT + tn.o00 + c);
            s01 = *(const u32x4*)(xT + tn.o01 + c);
            s10 = *(const u32x4*)(xT + tn.o10 + c);
            s11 = *(const u32x4*)(xT + tn.o11 + c);
        }
        const char* Ac = (const char*)&At[cur][0];
        char* An = (char*)&At[cur ^ 1][0];

        #pragma unroll
        for (int half = 0; half < 4; ++half){
            // ---- MFMA cluster: 2 K-steps ----
            __builtin_amdgcn_s_setprio(1);
            #pragma unroll
            for (int s = 0; s < 2; ++s){
                int step = half * 2 + s;
                int ck = step * 4 + g;
                s16x8 a[4];
                #pragma unroll
                for (int i = 0; i < 4; ++i){
                    int r = i * 16 + l15;
                    u32 boff = (u32)(r * 512) + (u32)((ck ^ (r & 15)) << 4);
                    a[i] = *(const s16x8*)(Ac + boff);
                }
                const u16* wrow = w3 + (size_t)(tap * 32 + step * 4 + g) * 2048
                                + (size_t)(wv * 32 + l15) * 8;
                s16x8 b0 = *(const s16x8*)(wrow);
                s16x8 b1 = *(const s16x8*)(wrow + 128);
                #pragma unroll
                for (int i = 0; i < 4; ++i){
                    acc[i][0] = __builtin_amdgcn_mfma_f32_16x16x32_bf16(a[i], b0, acc[i][0], 0, 0, 0);
                    acc[i][1] = __builtin_amdgcn_mfma_f32_16x16x32_bf16(a[i], b1, acc[i][1], 0, 0, 0);
                }
            }
            __builtin_amdgcn_s_setprio(0);

            if (pre){
                // commit sub-round `half`, then issue sub-round half+1
                int ck = k + half * 8;
                u32x4 outv;
                #pragma unroll
                for (int j = 0; j < 4; ++j)
                    outv[j] = blerp_pack(s00[j], s01[j], s10[j], s11[j],
                                         tn.w00, tn.w01, tn.w10, tn.w11);
                u32 boff = (u32)(p * 512) + (u32)((ck ^ (p & 15)) << 4);
                *(u32x4*)(An + boff) = outv;
                if (half < 3){
                    int c = (k + (half + 1) * 8) * 8;
                    s00 = *(const u32x4*)(xT + tn.o00 + c);
                    s01 = *(const u32x4*)(xT + tn.o01 + c);
                    s10 = *(const u32x4*)(xT + tn.o10 + c);
                    s11 = *(const u32x4*)(xT + tn.o11 + c);
                }
            }
        }
        __syncthreads();
        cur ^= 1;
    }

    // ---- epilogue: store conv f32 at global [m][o], accumulate GN stats ----
    float s0 = 0.f, s20 = 0.f;
    size_t mbase = (size_t)b * HW_;
    #pragma unroll
    for (int i = 0; i < 4; ++i){
        #pragma unroll
        for (int q = 0; q < 2; ++q){
            int oc = wv * 32 + q * 16 + l15;
            #pragma unroll
            for (int j = 0; j < 4; ++j){
                float v = acc[i][q][j];
                int pp = i * 16 + g * 4 + j;              // pixel in patch
                int mr_hw = (py0 + (pp >> 3)) * W_ + px0 + (pp & 7);
                convOut[(mbase + mr_hw) * 256 + oc] = v;
                s0 += v; s20 += v * v;
            }
        }
    }
    #pragma unroll
    for (int d = 32; d; d >>= 1){
        s0  += __shfl_xor(s0, d, 64);
        s20 += __shfl_xor(s20, d, 64);
    }
    if (lane == 0){
        atomicAdd(&stats[(b * 8 + wv) * 2 + 0], s0);
        atomicAdd(&stats[(b * 8 + wv) * 2 + 1], s20);
    }
}

// ---------------------------------------------------------------------------
// Kernel 4: GroupNorm(8) + ReLU, transposing [m][o] -> [b,o,h,w]
// ---------------------------------------------------------------------------
__global__ __launch_bounds__(256) void gn_final(
    const float* __restrict__ convOut, const float* __restrict__ stats,
    const float* __restrict__ gamma, const float* __restrict__ beta,
    float* __restrict__ out)
{
    __shared__ float t[64][257];
    int tid = threadIdx.x;
    int m0 = blockIdx.x * 64;
    int b = m0 / HW_;
    const f32x4* src = (const f32x4*)(convOut + (size_t)m0 * 256);
    #pragma unroll
    for (int it = 0; it < 16; ++it){
        int idx = it * 256 + tid;
        int r = idx >> 6;
        int c4 = idx & 63;
        f32x4 v = src[(size_t)r * 64 + c4];
        t[r][c4 * 4 + 0] = v[0];
        t[r][c4 * 4 + 1] = v[1];
        t[r][c4 * 4 + 2] = v[2];
        t[r][c4 * 4 + 3] = v[3];
    }
    __syncthreads();
    int lanem = tid & 63;
    int hw = (m0 - b * HW_) + lanem;
    float* dst = out + (size_t)b * O_ * HW_ + hw;
    const float invN = 1.f / 294912.f;   // 32 ch * 9216 px
    #pragma unroll 8
    for (int it = 0; it < 64; ++it){
        int o = it * 4 + (tid >> 6);
        int gidx = (b * 8 + (o >> 5)) * 2;
        float sm = stats[gidx + 0];
        float sq = stats[gidx + 1];
        float mu = sm * invN;
        float var = sq * invN - mu * mu;
        float inv = rsqrtf(var + 1e-5f);
        float sc = gamma[o] * inv;
        float sh = beta[o] - mu * sc;
        float v = t[lanem][o];
        dst[(size_t)o * HW_] = fmaxf(v * sc + sh, 0.f);
    }
}

// ---------------------------------------------------------------------------
extern "C" void kernel_launch(void* const* d_in, const int* in_sizes, int n_in,
                              void* d_out, int out_size, void* d_ws, size_t ws_size,
                              hipStream_t stream)
{
    const float* x     = (const float*)d_in[0];
    const float* off   = (const float*)d_in[1];
    const float* msk   = (const float*)d_in[2];
    const float* wt    = (const float*)d_in[3];
    const float* gamma = (const float*)d_in[4];
    const float* beta  = (const float*)d_in[5];
    float* out = (float*)d_out;

    char* ws = (char*)d_ws;
    u16*   xT      = (u16*)ws;                       // 18,874,368 B
    u16*   w3      = (u16*)(ws + 18874368);          //  1,179,648 B
    float* convOut = (float*)(ws + 20054016);        // 37,748,736 B
    float* stats   = (float*)(ws + 57802752);        //        256 B

    hipMemsetAsync(stats, 0, 256, stream);
    hipLaunchKernelGGL(transpose_x, dim3(9216), dim3(256), 0, stream, x, xT);
    hipLaunchKernelGGL(pack_w,      dim3(2304), dim3(256), 0, stream, wt, w3);
    hipLaunchKernelGGL(dcn_main,    dim3(576),  dim3(512), 0, stream,
                       off, msk, xT, w3, convOut, stats);
    hipLaunchKernelGGL(gn_final,    dim3(576),  dim3(256), 0, stream,
                       convOut, stats, gamma, beta, out);
}

// Round 14
// 167.091 us; speedup vs baseline: 1.3480x; 1.0244x over previous
//
#include <hip/hip_runtime.h>
#include <hip/hip_bf16.h>
#include <stdint.h>

typedef __attribute__((ext_vector_type(4))) float f32x4;
typedef __attribute__((ext_vector_type(8))) short s16x8;
typedef __attribute__((ext_vector_type(4))) unsigned int u32x4;
typedef unsigned short u16;
typedef unsigned int u32;

#define B_ 4
#define C_ 256
#define O_ 256
#define H_ 96
#define W_ 96
#define HW_ (H_*W_)      /* 9216 */
#define M_ (B_*HW_)      /* 36864 */

static __device__ __forceinline__ float asf(u32 u){
    union { u32 u; float f; } x; x.u = u; return x.f;
}
static __device__ __forceinline__ u16 f2bf(float f){
    union { float f; u32 u; } x; x.f = f;
    u32 u = x.u;
    u32 r = (u + 0x7fffu + ((u >> 16) & 1u)) >> 16;
    return (u16)r;
}
static __device__ __forceinline__ float bf2f(u16 u){
    union { u32 u; float f; } x; x.u = ((u32)u) << 16; return x.f;
}
// bilinear-combine a bf16 pair (packed in u32) from 4 source pairs, repack
static __device__ __forceinline__ u32 blerp_pack(u32 q00, u32 q01, u32 q10, u32 q11,
                                                 float w00, float w01, float w10, float w11)
{
    float f0 = asf(q00 << 16) * w00 + asf(q01 << 16) * w01
             + asf(q10 << 16) * w10 + asf(q11 << 16) * w11;
    float f1 = asf(q00) * w00 + asf(q01) * w01 + asf(q10) * w10 + asf(q11) * w11;
    float2 fp; fp.x = f0; fp.y = f1;
    __hip_bfloat162 hb = __float22bfloat162_rn(fp);
    union { __hip_bfloat162 h; u32 u; } cv; cv.h = hb;
    return cv.u;
}

// compact tap context: 4 weights + 4 x 32-bit element offsets into xT
struct TapCtx {
    float w00, w01, w10, w11;
    u32 o00, o01, o10, o11;
};

static __device__ __forceinline__ TapCtx tap_setup(
    int tap, int b, int h, int w, int hw,
    const float* __restrict__ off, const float* __restrict__ msk)
{
    TapCtx t;
    float dy = off[(size_t)(b * 18 + 2 * tap) * HW_ + hw];
    float dx = off[(size_t)(b * 18 + 2 * tap + 1) * HW_ + hw];
    float mk = msk[(size_t)(b * 9 + tap) * HW_ + hw];
    float py = (float)(h + tap / 3 - 1) + dy;
    float px = (float)(w + tap % 3 - 1) + dx;
    float fy = floorf(py), fx = floorf(px);
    float wy = py - fy, wx = px - fx;
    int y0 = (int)fy, x0 = (int)fx;
    int y1 = y0 + 1, x1 = x0 + 1;
    float w00 = (1.f - wy) * (1.f - wx) * mk;
    float w01 = (1.f - wy) * wx * mk;
    float w10 = wy * (1.f - wx) * mk;
    float w11 = wy * wx * mk;
    if (y0 < 0 || y0 >= H_) { w00 = 0.f; w01 = 0.f; }
    if (y1 < 0 || y1 >= H_) { w10 = 0.f; w11 = 0.f; }
    if (x0 < 0 || x0 >= W_) { w00 = 0.f; w10 = 0.f; }
    if (x1 < 0 || x1 >= W_) { w01 = 0.f; w11 = 0.f; }
    int cy0 = min(max(y0, 0), H_ - 1), cy1 = min(max(y1, 0), H_ - 1);
    int cx0 = min(max(x0, 0), W_ - 1), cx1 = min(max(x1, 0), W_ - 1);
    u32 rb = (u32)b * (u32)(HW_ * C_);
    t.o00 = rb + ((u32)(cy0 * W_ + cx0)) * C_;
    t.o01 = rb + ((u32)(cy0 * W_ + cx1)) * C_;
    t.o10 = rb + ((u32)(cy1 * W_ + cx0)) * C_;
    t.o11 = rb + ((u32)(cy1 * W_ + cx1)) * C_;
    t.w00 = w00; t.w01 = w01; t.w10 = w10; t.w11 = w11;
    return t;
}

// ---------------------------------------------------------------------------
// Kernel 1: fused prep.
//  blocks [0, 9216)      : transpose x [B,C,H,W] f32 -> xT [B,H,W,C] bf16
//  blocks [9216, 11520)  : pack weight [O,C,3,3] f32 -> W3 bf16
// ---------------------------------------------------------------------------
__global__ __launch_bounds__(256) void prep(const float* __restrict__ x,
                                            const float* __restrict__ wt,
                                            u16* __restrict__ xT,
                                            u16* __restrict__ w3)
{
    int bi = blockIdx.x;
    int tid = threadIdx.x;
    if (bi >= 9216){
        int n = (bi - 9216) * 256 + tid;        // < 589824 = 256*256*9
        int o = n / 2304;
        int rem = n - o * 2304;
        int c = rem / 9;
        int tap = rem - c * 9;
        int kidx = tap * 256 + c;
        w3[(size_t)(kidx >> 3) * 2048 + o * 8 + (kidx & 7)] = f2bf(wt[n]);
        return;
    }
    __shared__ float t[32][33];
    int tx = tid & 31, ty = tid >> 5;          // 32 x 8
    int w0 = (bi % 3) * 32;
    int c0 = ((bi / 3) % 8) * 32;
    int bh = bi / 24;                           // b*H + h  (0..383)
    int b = bh / H_, h = bh - b * H_;
    #pragma unroll
    for (int r = 0; r < 4; ++r){
        int c = c0 + ty + r * 8;
        t[ty + r * 8][tx] = x[(size_t)(b * C_ + c) * HW_ + h * W_ + w0 + tx];
    }
    __syncthreads();
    #pragma unroll
    for (int r = 0; r < 4; ++r){
        int w = w0 + ty + r * 8;
        xT[((size_t)(b * H_ + h) * W_ + w) * C_ + c0 + tx] = f2bf(t[tx][ty + r * 8]);
    }
}

// ---------------------------------------------------------------------------
// Kernel 2: deformable-conv implicit GEMM (R13 champion structure).
// 576 blocks x 512 threads (8 waves). Block = 8x8 patch, BM=64, BN=256;
// wave wv owns cols [wv*32, wv*32+32) (acc[4][2]). XCD-contiguous tiles.
// Double-buffered 2x32KB A-tile. Per tap: FOUR staged sub-rounds, each a
// single 16B chunk (4 loads, 16 VGPR live) issued before / committed after a
// 2-step MFMA cluster. ONE barrier per tap. __launch_bounds__(512,4): the
// 64-VGPR clamped allocation empirically beats plain (512) by ~15%.
// NEW vs R13: conv output stored as PACKED bf16 pairs (oc, oc+16) -> one u32
// per lane, 64B store segments; halves conv write and gn read traffic.
// ---------------------------------------------------------------------------
__global__ __launch_bounds__(512, 4) void dcn_main(
    const float* __restrict__ off, const float* __restrict__ msk,
    const u16* __restrict__ xT, const u16* __restrict__ w3,
    u32* __restrict__ convB, float* __restrict__ stats)
{
    __shared__ u16 At[2][64 * 256];  // 2 x 32 KB, rows 512B, 16B-chunk swz
    int tid = threadIdx.x;
    int lane = tid & 63;
    int wv = tid >> 6;               // 0..7 : 32-col chunk
    int l15 = lane & 15;
    int g = lane >> 4;               // 0..3

    int bid = blockIdx.x;
    int tile = (bid & 7) * 72 + (bid >> 3);     // 576 = 8*72, bijective
    int b = tile / 144;
    int t = tile - b * 144;
    int ty_ = t / 12, tx_ = t - ty_ * 12;
    int py0 = ty_ * 8, px0 = tx_ * 8;

    f32x4 acc[4][2];
    #pragma unroll
    for (int i = 0; i < 4; ++i)
        #pragma unroll
        for (int q = 0; q < 2; ++q)
            acc[i][q] = (f32x4){0.f, 0.f, 0.f, 0.f};

    // gather assignment: 8 threads per pixel, 4 chunks each (k,k+8,k+16,k+24)
    int p = tid >> 3;                // pixel 0..63 within patch
    int k = tid & 7;
    int h = py0 + (p >> 3);
    int w = px0 + (p & 7);
    int hw = h * W_ + w;

    // ---- prologue: gather tap 0 into At[0] ----
    {
        TapCtx tp = tap_setup(0, b, h, w, hw, off, msk);
        #pragma unroll
        for (int i = 0; i < 4; ++i){
            int ck = k + i * 8;
            int c = ck * 8;
            u32x4 q00 = *(const u32x4*)(xT + tp.o00 + c);
            u32x4 q01 = *(const u32x4*)(xT + tp.o01 + c);
            u32x4 q10 = *(const u32x4*)(xT + tp.o10 + c);
            u32x4 q11 = *(const u32x4*)(xT + tp.o11 + c);
            u32x4 outv;
            #pragma unroll
            for (int j = 0; j < 4; ++j)
                outv[j] = blerp_pack(q00[j], q01[j], q10[j], q11[j],
                                     tp.w00, tp.w01, tp.w10, tp.w11);
            u32 boff = (u32)(p * 512) + (u32)((ck ^ (p & 15)) << 4);
            *(u32x4*)((char*)&At[0][0] + boff) = outv;
        }
    }
    __syncthreads();

    int cur = 0;
    for (int tap = 0; tap < 9; ++tap){
        bool pre = (tap < 8);
        TapCtx tn;
        u32x4 s00, s01, s10, s11;
        if (pre){
            tn = tap_setup(tap + 1, b, h, w, hw, off, msk);
            int c = k * 8;                         // sub-round 0: chunk k
            s00 = *(const u32x4*)(xT + tn.o00 + c);
            s01 = *(const u32x4*)(xT + tn.o01 + c);
            s10 = *(const u32x4*)(xT + tn.o10 + c);
            s11 = *(const u32x4*)(xT + tn.o11 + c);
        }
        const char* Ac = (const char*)&At[cur][0];
        char* An = (char*)&At[cur ^ 1][0];

        #pragma unroll
        for (int half = 0; half < 4; ++half){
            // ---- MFMA cluster: 2 K-steps ----
            __builtin_amdgcn_s_setprio(1);
            #pragma unroll
            for (int s = 0; s < 2; ++s){
                int step = half * 2 + s;
                int ck = step * 4 + g;
                s16x8 a[4];
                #pragma unroll
                for (int i = 0; i < 4; ++i){
                    int r = i * 16 + l15;
                    u32 boff = (u32)(r * 512) + (u32)((ck ^ (r & 15)) << 4);
                    a[i] = *(const s16x8*)(Ac + boff);
                }
                const u16* wrow = w3 + (size_t)(tap * 32 + step * 4 + g) * 2048
                                + (size_t)(wv * 32 + l15) * 8;
                s16x8 b0 = *(const s16x8*)(wrow);
                s16x8 b1 = *(const s16x8*)(wrow + 128);
                #pragma unroll
                for (int i = 0; i < 4; ++i){
                    acc[i][0] = __builtin_amdgcn_mfma_f32_16x16x32_bf16(a[i], b0, acc[i][0], 0, 0, 0);
                    acc[i][1] = __builtin_amdgcn_mfma_f32_16x16x32_bf16(a[i], b1, acc[i][1], 0, 0, 0);
                }
            }
            __builtin_amdgcn_s_setprio(0);

            if (pre){
                // commit sub-round `half`, then issue sub-round half+1
                int ck = k + half * 8;
                u32x4 outv;
                #pragma unroll
                for (int j = 0; j < 4; ++j)
                    outv[j] = blerp_pack(s00[j], s01[j], s10[j], s11[j],
                                         tn.w00, tn.w01, tn.w10, tn.w11);
                u32 boff = (u32)(p * 512) + (u32)((ck ^ (p & 15)) << 4);
                *(u32x4*)(An + boff) = outv;
                if (half < 3){
                    int c = (k + (half + 1) * 8) * 8;
                    s00 = *(const u32x4*)(xT + tn.o00 + c);
                    s01 = *(const u32x4*)(xT + tn.o01 + c);
                    s10 = *(const u32x4*)(xT + tn.o10 + c);
                    s11 = *(const u32x4*)(xT + tn.o11 + c);
                }
            }
        }
        __syncthreads();
        cur ^= 1;
    }

    // ---- epilogue: store conv as packed bf16 pairs (oc, oc+16) -> u32 at
    // convB[m*128 + wv*16 + l15]; accumulate GN stats from f32 accs ----
    float s0 = 0.f, s20 = 0.f;
    size_t mbase = (size_t)b * HW_;
    #pragma unroll
    for (int i = 0; i < 4; ++i){
        #pragma unroll
        for (int j = 0; j < 4; ++j){
            float v0 = acc[i][0][j];
            float v1 = acc[i][1][j];
            int pp = i * 16 + g * 4 + j;              // pixel in patch
            int mr_hw = (py0 + (pp >> 3)) * W_ + px0 + (pp & 7);
            u32 pk = ((u32)f2bf(v1) << 16) | (u32)f2bf(v0);
            convB[(mbase + mr_hw) * 128 + wv * 16 + l15] = pk;
            s0 += v0 + v1; s20 += v0 * v0 + v1 * v1;
        }
    }
    #pragma unroll
    for (int d = 32; d; d >>= 1){
        s0  += __shfl_xor(s0, d, 64);
        s20 += __shfl_xor(s20, d, 64);
    }
    if (lane == 0){
        atomicAdd(&stats[(b * 8 + wv) * 2 + 0], s0);
        atomicAdd(&stats[(b * 8 + wv) * 2 + 1], s20);
    }
}

// ---------------------------------------------------------------------------
// Kernel 3: GroupNorm(8) + ReLU. Reads packed-bf16 conv (u32 at
// [m][idx=wv*16+l15] <-> channels (idx>>4)*32+(idx&15) and +16), LDS
// transpose, writes f32 [b,o,h,w].
// ---------------------------------------------------------------------------
__global__ __launch_bounds__(256) void gn_final(
    const u32* __restrict__ convB, const float* __restrict__ stats,
    const float* __restrict__ gamma, const float* __restrict__ beta,
    float* __restrict__ out)
{
    __shared__ float t[64][257];
    int tid = threadIdx.x;
    int m0 = blockIdx.x * 64;
    int b = m0 / HW_;
    const u32x4* src = (const u32x4*)(convB + (size_t)m0 * 128);
    #pragma unroll
    for (int it = 0; it < 8; ++it){
        int idx = it * 256 + tid;        // 0..2047 : (row, u32x4-chunk of 4)
        int r = idx >> 5;
        int c4 = idx & 31;
        u32x4 v = src[(size_t)r * 32 + c4];
        #pragma unroll
        for (int jj = 0; jj < 4; ++jj){
            int pos = c4 * 4 + jj;                    // u32 index 0..127
            int o_lo = ((pos >> 4) << 5) + (pos & 15);
            t[r][o_lo]      = bf2f((u16)(v[jj] & 0xffff));
            t[r][o_lo + 16] = bf2f((u16)(v[jj] >> 16));
        }
    }
    __syncthreads();
    int lanem = tid & 63;
    int hw = (m0 - b * HW_) + lanem;
    float* dst = out + (size_t)b * O_ * HW_ + hw;
    const float invN = 1.f / 294912.f;   // 32 ch * 9216 px
    #pragma unroll 8
    for (int it = 0; it < 64; ++it){
        int o = it * 4 + (tid >> 6);
        int gidx = (b * 8 + (o >> 5)) * 2;
        float sm = stats[gidx + 0];
        float sq = stats[gidx + 1];
        float mu = sm * invN;
        float var = sq * invN - mu * mu;
        float inv = rsqrtf(var + 1e-5f);
        float sc = gamma[o] * inv;
        float sh = beta[o] - mu * sc;
        float v = t[lanem][o];
        dst[(size_t)o * HW_] = fmaxf(v * sc + sh, 0.f);
    }
}

// ---------------------------------------------------------------------------
extern "C" void kernel_launch(void* const* d_in, const int* in_sizes, int n_in,
                              void* d_out, int out_size, void* d_ws, size_t ws_size,
                              hipStream_t stream)
{
    const float* x     = (const float*)d_in[0];
    const float* off   = (const float*)d_in[1];
    const float* msk   = (const float*)d_in[2];
    const float* wt    = (const float*)d_in[3];
    const float* gamma = (const float*)d_in[4];
    const float* beta  = (const float*)d_in[5];
    float* out = (float*)d_out;

    char* ws = (char*)d_ws;
    u16*   xT    = (u16*)ws;                       // 18,874,368 B
    u16*   w3    = (u16*)(ws + 18874368);          //  1,179,648 B
    u32*   convB = (u32*)(ws + 20054016);          // 18,874,368 B (packed bf16)
    float* stats = (float*)(ws + 57802752);        //        256 B

    hipMemsetAsync(stats, 0, 256, stream);
    hipLaunchKernelGGL(prep,     dim3(11520), dim3(256), 0, stream, x, wt, xT, w3);
    hipLaunchKernelGGL(dcn_main, dim3(576),   dim3(512), 0, stream,
                       off, msk, xT, w3, convB, stats);
    hipLaunchKernelGGL(gn_final, dim3(576),   dim3(256), 0, stream,
                       convB, stats, gamma, beta, out);
}